// Round 1
// baseline (450.472 us; speedup 1.0000x reference)
//
#include <hip/hip_runtime.h>
#include <math.h>

typedef __attribute__((ext_vector_type(8))) short bf16x8;
typedef __attribute__((ext_vector_type(4))) float f32x4;
typedef unsigned short u16;
typedef unsigned int u32;

#define N_TOK 4096
#define HID   2048
#define N_HEAD 16
#define HDIM  128
#define QK_SCALE 0.08838834764831845f /* 128^-0.5 */
#define LOG2E_   1.4426950408889634f

__device__ __forceinline__ u16 f2bf(float x) {
  union { float f; u32 u; } v; v.f = x;
  u32 r = v.u + 0x7fffu + ((v.u >> 16) & 1u);
  return (u16)(r >> 16);
}

__device__ __forceinline__ void async16(const void* g, void* l) {
  __builtin_amdgcn_global_load_lds(
      (const __attribute__((address_space(1))) void*)g,
      (__attribute__((address_space(3))) void*)l, 16, 0, 0);
}

#define MFMA(a, b, c) __builtin_amdgcn_mfma_f32_16x16x32_bf16((a), (b), (c), 0, 0, 0)

// ---------------- rope tables: cos/sin per (token, pair) ----------------
__global__ void k_rope(float* __restrict__ cosT, float* __restrict__ sinT) {
  int l = blockIdx.x;         // 4096
  int p = threadIdx.x;        // 64 pairs
  int c1 = l >> 10, c2 = (l >> 5) & 31, c3 = l & 31;
  int pos, j; float dim;
  if (p < 8)       { pos = c1; j = p;      dim = 16.f; }
  else if (p < 36) { pos = c2; j = p - 8;  dim = 56.f; }
  else             { pos = c3; j = p - 36; dim = 56.f; }
  float freq = exp2f(-8.0f * (2.0f * (float)j) / dim);  // 256 = 2^8
  float ang = (float)pos * freq;
  float s, c;
  sincosf(ang, &s, &c);
  cosT[l * 64 + p] = c;
  sinT[l * 64 + p] = s;
}

// ---------------- convert X fp32 -> bf16 ----------------
__global__ __launch_bounds__(256) void k_cvt_x(const float* __restrict__ X, u16* __restrict__ Xb) {
  int i = blockIdx.x * 256 + threadIdx.x;       // 4 elems each
  float4 v = ((const float4*)X)[i];
  ushort4 o;
  o.x = f2bf(v.x); o.y = f2bf(v.y); o.z = f2bf(v.z); o.w = f2bf(v.w);
  ((ushort4*)Xb)[i] = o;
}

// ---------------- transpose+convert W: WT[z][n][k] = bf16(W[k][n]) ----------------
__global__ __launch_bounds__(256) void k_tw(const float* __restrict__ Wq, const float* __restrict__ Wk,
                                            const float* __restrict__ Wv, const float* __restrict__ Wo,
                                            u16* __restrict__ WT) {
  int z = blockIdx.z;
  const float* W = (z == 0) ? Wq : (z == 1) ? Wk : (z == 2) ? Wv : Wo;
  u16* dst = WT + (size_t)z * 2048 * 2048;
  __shared__ __align__(16) float T[64][69];
  int n0 = blockIdx.x * 64, k0 = blockIdx.y * 64;
  int tid = threadIdx.x;
  int r = tid >> 4, c4 = tid & 15;
#pragma unroll
  for (int i = 0; i < 4; ++i) {
    int row = r + i * 16;
    float4 v = *(const float4*)(W + (size_t)(k0 + row) * 2048 + n0 + c4 * 4);
    T[row][c4 * 4 + 0] = v.x; T[row][c4 * 4 + 1] = v.y;
    T[row][c4 * 4 + 2] = v.z; T[row][c4 * 4 + 3] = v.w;
  }
  __syncthreads();
#pragma unroll
  for (int i = 0; i < 4; ++i) {
    int row = r + i * 16;  // n-local
    ushort4 o;
    o.x = f2bf(T[c4 * 4 + 0][row]);
    o.y = f2bf(T[c4 * 4 + 1][row]);
    o.z = f2bf(T[c4 * 4 + 2][row]);
    o.w = f2bf(T[c4 * 4 + 3][row]);
    *(ushort4*)(dst + (size_t)(n0 + row) * 2048 + k0 + c4 * 4) = o;
  }
}

// ---------------- GEMM: C[M,N] = A[M,K](bf16) * Bt[N,K]^T(bf16) + bias ----------------
__global__ __launch_bounds__(256) void k_gemm(const u16* __restrict__ A, const u16* __restrict__ Bt,
                                              const float* __restrict__ bias, float* __restrict__ C,
                                              int M, int N, int K) {
  __shared__ __align__(16) char lds[2][2][16384];  // [buf][A/B][128 rows][64 k] swizzled
  int nbn = N >> 7;
  int nwg = gridDim.x;
  int wg = (int)blockIdx.x;
  int cpx = nwg >> 3;               // nwg % 8 == 0 for all our launches
  wg = (wg & 7) * cpx + (wg >> 3);  // XCD swizzle (T1)
  int bm = wg / nbn, bn = wg - bm * nbn;
  int tid = threadIdx.x;
  int lane = tid & 63, wid = tid >> 6;
  int g = lane >> 4, cl = lane & 15;
  int wm = (wid >> 1) * 64, wn = (wid & 1) * 64;
  const char* Ab0 = (const char*)A + (size_t)bm * 128 * (size_t)(K * 2);
  const char* Bb0 = (const char*)Bt + (size_t)bn * 128 * (size_t)(K * 2);
  int nk = K >> 6;

  f32x4 acc[4][4] = {};

  auto stage = [&](int buf, int kt) {
    const char* Ab = Ab0 + kt * 128;  // kt*64 elems * 2B
    const char* Bb = Bb0 + kt * 128;
    char* La = &lds[buf][0][0];
    char* Lb = &lds[buf][1][0];
#pragma unroll
    for (int i = 0; i < 4; ++i) {
      int flat = tid + 256 * i;
      int row = flat >> 3, sb = flat & 7;
      async16(Ab + (size_t)row * (K * 2) + ((sb ^ (row & 7)) << 4), La + flat * 16);
    }
#pragma unroll
    for (int i = 0; i < 4; ++i) {
      int flat = tid + 256 * i;
      int row = flat >> 3, sb = flat & 7;
      async16(Bb + (size_t)row * (K * 2) + ((sb ^ (row & 7)) << 4), Lb + flat * 16);
    }
  };

  stage(0, 0);
  __syncthreads();
  for (int kt = 0; kt < nk; ++kt) {
    int cur = kt & 1;
    if (kt + 1 < nk) stage(cur ^ 1, kt + 1);
    const char* La = &lds[cur][0][0];
    const char* Lb = &lds[cur][1][0];
#pragma unroll
    for (int ks = 0; ks < 2; ++ks) {
      bf16x8 af[4], bfr[4];
#pragma unroll
      for (int mf = 0; mf < 4; ++mf) {
        int row = wm + mf * 16 + cl;
        af[mf] = *(const bf16x8*)(La + row * 128 + (((ks * 4 + g) ^ (row & 7)) << 4));
      }
#pragma unroll
      for (int nf = 0; nf < 4; ++nf) {
        int row = wn + nf * 16 + cl;
        bfr[nf] = *(const bf16x8*)(Lb + row * 128 + (((ks * 4 + g) ^ (row & 7)) << 4));
      }
#pragma unroll
      for (int mf = 0; mf < 4; ++mf)
#pragma unroll
        for (int nf = 0; nf < 4; ++nf)
          acc[mf][nf] = MFMA(af[mf], bfr[nf], acc[mf][nf]);
    }
    __syncthreads();
  }
#pragma unroll
  for (int mf = 0; mf < 4; ++mf)
#pragma unroll
    for (int nf = 0; nf < 4; ++nf) {
      int col = bn * 128 + wn + nf * 16 + cl;
      float b = bias[col];
#pragma unroll
      for (int r = 0; r < 4; ++r) {
        int row = bm * 128 + wm + mf * 16 + g * 4 + r;
        C[(size_t)row * N + col] = acc[mf][nf][r] + b;
      }
    }
}

// ---------------- fused RMSNorm + RoPE + tile-layout write (Q or K) ----------------
// one wave per (head, token). Q: linear [h][tile][t][128] *SCALE*log2e. K: bank-swizzle baked.
__global__ __launch_bounds__(256) void k_prep_qk(const float* __restrict__ src, const float* __restrict__ gg,
                                                 const float* __restrict__ cosT, const float* __restrict__ sinT,
                                                 u16* __restrict__ dst, int isk) {
  int job = blockIdx.x * 4 + (threadIdx.x >> 6);  // 65536 jobs
  int lane = threadIdx.x & 63;
  int tok = job & 4095, h = job >> 12;
  const float* row = src + (size_t)tok * 2048 + h * 128;
  float2 x = *(const float2*)(row + lane * 2);
  float ss = x.x * x.x + x.y * x.y;
#pragma unroll
  for (int m = 1; m < 64; m <<= 1) ss += __shfl_xor(ss, m, 64);
  float rms = rsqrtf(ss * (1.0f / 128.0f) + 1e-6f);
  float x0 = x.x * rms * gg[lane * 2];
  float x1 = x.y * rms * gg[lane * 2 + 1];
  float c = cosT[tok * 64 + lane], s = sinT[tok * 64 + lane];
  float y0 = x0 * c - x1 * s;
  float y1 = x1 * c + x0 * s;
  if (!isk) { y0 *= QK_SCALE * LOG2E_; y1 *= QK_SCALE * LOG2E_; }
  u32 pk = (u32)f2bf(y0) | ((u32)f2bf(y1) << 16);
  int c1 = tok >> 10, c2 = (tok >> 5) & 31, c3 = tok & 31;
  int n = (c2 >> 3) * 4 + (c3 >> 3);
  int t = c1 * 64 + (c2 & 7) * 8 + (c3 & 7);
  size_t rowidx = (size_t)(h * 16 + n) * 256 + t;
  if (!isk) {
    ((u32*)dst)[rowidx * 64 + lane] = pk;
  } else {
    char* base = (char*)dst + rowidx * 256;
    *(u32*)(base + ((((lane >> 2) ^ (t & 7)) << 4) + (lane & 3) * 4)) = pk;
  }
}

// ---------------- V: convert + transpose to [h][tile][chunk][d][64tok], swizzle baked ----------------
__global__ __launch_bounds__(256) void k_prep_v(const float* __restrict__ src, u16* __restrict__ Vt) {
  __shared__ __align__(16) u16 T[128][72];
  int tid = threadIdx.x;
  int h = blockIdx.x >> 6, n = (blockIdx.x >> 2) & 15, ch = blockIdx.x & 3;
  int d2 = n >> 2, d3 = n & 3;
  int tc = tid >> 2, cq = tid & 3;
  int tok = (ch * 32 + d2 * 8 + (tc >> 3)) * 32 + d3 * 8 + (tc & 7);
  const float* sp = src + (size_t)tok * 2048 + h * 128;
#pragma unroll
  for (int i = 0; i < 8; ++i) {
    int d0 = cq * 4 + i * 16;
    float4 v = *(const float4*)(sp + d0);
    T[d0 + 0][tc] = f2bf(v.x); T[d0 + 1][tc] = f2bf(v.y);
    T[d0 + 2][tc] = f2bf(v.z); T[d0 + 3][tc] = f2bf(v.w);
  }
  __syncthreads();
  int d = tid >> 1, half = tid & 1;
  char* dstb = (char*)Vt + ((size_t)((h * 16 + n) * 4 + ch) * 128 + d) * 128;
#pragma unroll
  for (int b = 0; b < 4; ++b) {
    int blk = half * 4 + b;
    uint4 val = *(const uint4*)&T[d][blk * 8];
    *(uint4*)(dstb + ((blk ^ (d & 7)) << 4)) = val;
  }
}

// ---------------- sliding tiled attention ----------------
// 1 block per (head, qtile); 8 waves x 32 q rows; KV chunks of 64, double-buffered.
__global__ __launch_bounds__(512) void k_attn(const u16* __restrict__ Qt, const u16* __restrict__ Kt,
                                              const u16* __restrict__ Vt, u16* __restrict__ AO) {
  __shared__ __align__(16) char Kl[2][16384];   // [64 kv][128 d] swizzled
  __shared__ __align__(16) char Vl[2][16384];   // [128 d][64 kv] swizzled
  __shared__ __align__(16) char Pl[8][4096];    // per-wave [32 q][64 kv] swizzled
  int tid = threadIdx.x;
  int lane = tid & 63, wid = tid >> 6;
  int g = lane >> 4, cl = lane & 15;
  int h = blockIdx.x >> 4, n = blockIdx.x & 15;
  int d2 = n >> 2, d3 = n & 3;
  int s2 = d2 - 1; s2 = s2 < 0 ? 0 : (s2 > 1 ? 1 : s2);
  int s3 = d3 - 1; s3 = s3 < 0 ? 0 : (s3 > 1 ? 1 : s3);
  int q0 = wid * 32;

  // Q fragments (B-operand): qf[nq][ks]
  bf16x8 qf[2][4];
  const char* Qb = (const char*)Qt + (size_t)(h * 16 + n) * 256 * 256;
#pragma unroll
  for (int nq = 0; nq < 2; ++nq)
#pragma unroll
    for (int kf = 0; kf < 4; ++kf)
      qf[nq][kf] = *(const bf16x8*)(Qb + (q0 + nq * 16 + cl) * 256 + kf * 64 + g * 16);

  f32x4 o[2][8] = {};
  float ms0 = -__builtin_inff(), ms1 = -__builtin_inff();
  float ls0 = 0.f, ls1 = 0.f;

  auto stage = [&](int buf, int c) {
    int kvi = c >> 2, cc = c & 3;
    int i2 = kvi / 3, i3 = kvi - i2 * 3;
    int kvt = (s2 + i2) * 4 + (s3 + i3);
    const char* Kb = (const char*)Kt + ((size_t)((h * 16 + kvt) * 256 + cc * 64)) * 256;
    const char* Vb = (const char*)Vt + ((size_t)((h * 16 + kvt) * 4 + cc)) * 16384;
#pragma unroll
    for (int i = 0; i < 2; ++i) {
      int flat = tid + 512 * i;
      async16(Kb + flat * 16, &Kl[buf][0] + flat * 16);
      async16(Vb + flat * 16, &Vl[buf][0] + flat * 16);
    }
  };

  stage(0, 0);
  __syncthreads();

  char* Pw = &Pl[wid][0];
  for (int c = 0; c < 36; ++c) {
    int cur = c & 1;
    if (c + 1 < 36) stage(cur ^ 1, c + 1);
    const char* Kc = &Kl[cur][0];
    // S^T = K x Q : st[mk][nq], row=kv local, col=q local
    f32x4 st[4][2] = {};
#pragma unroll
    for (int ks = 0; ks < 4; ++ks) {
      bf16x8 af[4];
#pragma unroll
      for (int mk = 0; mk < 4; ++mk) {
        int row = mk * 16 + cl;
        af[mk] = *(const bf16x8*)(Kc + row * 256 + (((ks * 4 + g) ^ (row & 7)) << 4));
      }
#pragma unroll
      for (int mk = 0; mk < 4; ++mk) {
        st[mk][0] = MFMA(af[mk], qf[0][ks], st[mk][0]);
        st[mk][1] = MFMA(af[mk], qf[1][ks], st[mk][1]);
      }
    }
    // online softmax (col layout; scores already * SCALE*log2e)
    float al0, al1;
    {
      float cm = st[0][0][0];
#pragma unroll
      for (int mk = 0; mk < 4; ++mk)
#pragma unroll
        for (int r = 0; r < 4; ++r) cm = fmaxf(cm, st[mk][0][r]);
      cm = fmaxf(cm, __shfl_xor(cm, 16, 64));
      cm = fmaxf(cm, __shfl_xor(cm, 32, 64));
      float mn = fmaxf(ms0, cm);
      al0 = exp2f(ms0 - mn);
      float rs = 0.f;
#pragma unroll
      for (int mk = 0; mk < 4; ++mk)
#pragma unroll
        for (int r = 0; r < 4; ++r) {
          float p = exp2f(st[mk][0][r] - mn);
          st[mk][0][r] = p; rs += p;
        }
      rs += __shfl_xor(rs, 16, 64);
      rs += __shfl_xor(rs, 32, 64);
      ls0 = ls0 * al0 + rs; ms0 = mn;
    }
    {
      float cm = st[0][1][0];
#pragma unroll
      for (int mk = 0; mk < 4; ++mk)
#pragma unroll
        for (int r = 0; r < 4; ++r) cm = fmaxf(cm, st[mk][1][r]);
      cm = fmaxf(cm, __shfl_xor(cm, 16, 64));
      cm = fmaxf(cm, __shfl_xor(cm, 32, 64));
      float mn = fmaxf(ms1, cm);
      al1 = exp2f(ms1 - mn);
      float rs = 0.f;
#pragma unroll
      for (int mk = 0; mk < 4; ++mk)
#pragma unroll
        for (int r = 0; r < 4; ++r) {
          float p = exp2f(st[mk][1][r] - mn);
          st[mk][1][r] = p; rs += p;
        }
      rs += __shfl_xor(rs, 16, 64);
      rs += __shfl_xor(rs, 32, 64);
      ls1 = ls1 * al1 + rs; ms1 = mn;
    }
    // P -> per-wave LDS (bf16, swizzled)
#pragma unroll
    for (int nq = 0; nq < 2; ++nq) {
      int q = nq * 16 + cl;
#pragma unroll
      for (int mk = 0; mk < 4; ++mk)
#pragma unroll
        for (int rp = 0; rp < 2; ++rp) {
          u32 pk = (u32)f2bf(st[mk][nq][rp * 2]) | ((u32)f2bf(st[mk][nq][rp * 2 + 1]) << 16);
          int kv = mk * 16 + g * 4 + rp * 2;
          *(u32*)(Pw + q * 128 + (((kv >> 3) ^ (q & 7)) << 4) + (kv & 7) * 2) = pk;
        }
    }
    // rescale O (row layout: q = 16*mo + 4g + r)
    float ar0[4], ar1[4];
#pragma unroll
    for (int r = 0; r < 4; ++r) {
      ar0[r] = __shfl(al0, g * 4 + r, 64);
      ar1[r] = __shfl(al1, g * 4 + r, 64);
    }
#pragma unroll
    for (int nd = 0; nd < 8; ++nd)
#pragma unroll
      for (int r = 0; r < 4; ++r) {
        o[0][nd][r] *= ar0[r];
        o[1][nd][r] *= ar1[r];
      }
    // PV
    const char* Vc = &Vl[cur][0];
#pragma unroll
    for (int ks = 0; ks < 2; ++ks) {
      bf16x8 pf0, pf1, vf[8];
      {
        int q = cl;
        pf0 = *(const bf16x8*)(Pw + q * 128 + (((ks * 4 + g) ^ (q & 7)) << 4));
        q = 16 + cl;
        pf1 = *(const bf16x8*)(Pw + q * 128 + (((ks * 4 + g) ^ (q & 7)) << 4));
      }
#pragma unroll
      for (int nd = 0; nd < 8; ++nd) {
        int d = nd * 16 + cl;
        vf[nd] = *(const bf16x8*)(Vc + d * 128 + (((ks * 4 + g) ^ (d & 7)) << 4));
      }
#pragma unroll
      for (int nd = 0; nd < 8; ++nd) {
        o[0][nd] = MFMA(pf0, vf[nd], o[0][nd]);
        o[1][nd] = MFMA(pf1, vf[nd], o[1][nd]);
      }
    }
    __syncthreads();
  }
  // epilogue: /l, untile, write bf16 [tok][h*128+d]
  float lr0[4], lr1[4];
#pragma unroll
  for (int r = 0; r < 4; ++r) {
    lr0[r] = 1.0f / __shfl(ls0, g * 4 + r, 64);
    lr1[r] = 1.0f / __shfl(ls1, g * 4 + r, 64);
  }
#pragma unroll
  for (int mo = 0; mo < 2; ++mo)
#pragma unroll
    for (int r = 0; r < 4; ++r) {
      int t = q0 + mo * 16 + g * 4 + r;
      int t1 = t >> 6, t2 = (t >> 3) & 7, t3 = t & 7;
      int tok = (t1 * 32 + d2 * 8 + t2) * 32 + d3 * 8 + t3;
      u16* orow = AO + (size_t)tok * HID + h * HDIM;
      float lr = (mo == 0) ? lr0[r] : lr1[r];
#pragma unroll
      for (int nd = 0; nd < 8; ++nd)
        orow[nd * 16 + cl] = f2bf(o[mo][nd][r] * lr);
    }
}

// ---------------- launcher ----------------
extern "C" void kernel_launch(void* const* d_in, const int* in_sizes, int n_in,
                              void* d_out, int out_size, void* d_ws, size_t ws_size,
                              hipStream_t stream) {
  const float* X  = (const float*)d_in[0];
  const float* Wq = (const float*)d_in[1];
  const float* bq = (const float*)d_in[2];
  const float* Wk = (const float*)d_in[3];
  const float* bk = (const float*)d_in[4];
  const float* Wv = (const float*)d_in[5];
  const float* bv = (const float*)d_in[6];
  const float* Wo = (const float*)d_in[7];
  const float* bo = (const float*)d_in[8];
  const float* gq = (const float*)d_in[9];
  const float* gk = (const float*)d_in[10];

  char* ws = (char*)d_ws;
  size_t off = 0;
  auto alloc = [&](size_t bytes) { void* p = ws + off; off = (off + bytes + 255) & ~(size_t)255; return p; };
  u16*   Xb   = (u16*)alloc((size_t)N_TOK * HID * 2);
  u16*   WT   = (u16*)alloc((size_t)4 * 2048 * 2048 * 2);
  float* PF   = (float*)alloc((size_t)N_TOK * HID * 4);   // reused for q,k,v fp32
  float* COS  = (float*)alloc((size_t)N_TOK * 64 * 4);
  float* SIN  = (float*)alloc((size_t)N_TOK * 64 * 4);
  u16*   Qt   = (u16*)alloc((size_t)N_TOK * HID * 2);
  u16*   Kt   = (u16*)alloc((size_t)N_TOK * HID * 2);
  u16*   Vt   = (u16*)alloc((size_t)N_TOK * HID * 2);
  u16*   AO   = (u16*)alloc((size_t)N_TOK * HID * 2);
  float* OUT  = (float*)d_out;

  k_rope<<<N_TOK, 64, 0, stream>>>(COS, SIN);
  k_cvt_x<<<(N_TOK * HID / 4) / 256, 256, 0, stream>>>(X, Xb);
  k_tw<<<dim3(32, 32, 4), 256, 0, stream>>>(Wq, Wk, Wv, Wo, WT);

  // Q
  k_gemm<<<512, 256, 0, stream>>>(Xb, WT + (size_t)0 * 2048 * 2048, bq, PF, 4096, 2048, 2048);
  k_prep_qk<<<16384, 256, 0, stream>>>(PF, gq, COS, SIN, Qt, 0);
  // K
  k_gemm<<<512, 256, 0, stream>>>(Xb, WT + (size_t)1 * 2048 * 2048, bk, PF, 4096, 2048, 2048);
  k_prep_qk<<<16384, 256, 0, stream>>>(PF, gk, COS, SIN, Kt, 1);
  // V
  k_gemm<<<512, 256, 0, stream>>>(Xb, WT + (size_t)2 * 2048 * 2048, bv, PF, 4096, 2048, 2048);
  k_prep_v<<<1024, 256, 0, stream>>>(PF, Vt);

  k_attn<<<256, 512, 0, stream>>>(Qt, Kt, Vt, AO);

  k_gemm<<<512, 256, 0, stream>>>(AO, WT + (size_t)3 * 2048 * 2048, bo, OUT, 4096, 2048, 2048);
}